// Round 3
// baseline (15525.270 us; speedup 1.0000x reference)
//
#include <hip/hip_runtime.h>
#include <hip/hip_bf16.h>
#include <stdint.h>

// 2-layer LSTM, B=32 T=1024 D=256 H=512, fc -> 256.
// Strategy: split-bf16 MFMA GEMMs for input projections (xp stored fp16);
// persistent weight-stationary recurrence (32 blocks, Wh frags in VGPRs for
// all 1024 steps) with agent-scope flag handshake for the per-step h exchange.
// Workspace requirement: ~207 MiB.

typedef __attribute__((ext_vector_type(8))) short bf16x8;
typedef __attribute__((ext_vector_type(4))) float f32x4;
typedef unsigned short u16;

#define TSEQ 1024

static __device__ __forceinline__ float fsig(float x){ return 1.0f/(1.0f+__expf(-x)); }
static __device__ __forceinline__ float ftanh_(float x){ return 2.0f/(1.0f+__expf(-2.0f*x)) - 1.0f; }
static __device__ __forceinline__ u16 f2bf(float v){
  __hip_bfloat16 b = __float2bfloat16(v);
  return *reinterpret_cast<u16*>(&b);
}
static __device__ __forceinline__ float bf2f(u16 u){
  __hip_bfloat16 b; *reinterpret_cast<u16*>(&b) = u;
  return __bfloat162float(b);
}

// async global->LDS, 16B per lane; LDS dest = uniform base + lane*16
#define GLD_LDS16(g, l) \
  __builtin_amdgcn_global_load_lds((const __attribute__((address_space(1))) uint32_t*)(g), \
                                   (__attribute__((address_space(3))) uint32_t*)(l), 16, 0, 0)

// ---------------------------------------------------------------- utilities
__global__ void split_f32(const float* __restrict__ src, u16* __restrict__ hi,
                          u16* __restrict__ lo, const int n)
{
  for (int i = blockIdx.x*blockDim.x + threadIdx.x; i < n; i += gridDim.x*blockDim.x){
    const float v = src[i];
    const u16 h = f2bf(v);
    hi[i] = h;
    lo[i] = f2bf(v - bf2f(h));
  }
}

__global__ void vec_add(const float* __restrict__ a, const float* __restrict__ b,
                        float* __restrict__ c, const int n)
{
  const int i = blockIdx.x*blockDim.x + threadIdx.x;
  if (i < n) c[i] = a[i] + b[i];
}

// zero h_{-1} for layer0 (hs0h slot 0) and layer1 (ring slot 3)
__global__ void init_state(u16* hs0h, u16* ringh, u16* ringl)
{
  const int i = blockIdx.x*256 + threadIdx.x;       // 16384 = 32*512
  const int b = i >> 9, h = i & 511;
  const long a = (long)b*524800 + h;                // (b*1025 + 0)*512 + h
  hs0h[a] = 0;
  ringh[3*16384 + i] = 0; ringl[3*16384 + i] = 0;
}

// ------------------------------------------------------ split-bf16 MFMA GEMM
// C[m][n] = sum_k A[m][k]*W[n][k] + bias[n],  M=32768 N=2048, K in {256,512}
// A = Ahi+Alo, W = Whi+Wlo. three=1: Ah*Wh + Ah*Wl + Al*Wh; three=0: Ah*(Wh+Wl).
// rowmode=1: A rows are hs0 layout [B][T+1][512] at slot t+1 (m = b*1024+t).
// Output C is fp16 (pre-activation values are O(1); fp16 err ~3e-4).
// LDS holds tiles already in packed MFMA-fragment order -> conflict-free b128.
__global__ __launch_bounds__(256, 2) void gemm_split(
    const u16* __restrict__ Ahi, const u16* __restrict__ Alo,
    const u16* __restrict__ Whi, const u16* __restrict__ Wlo,
    const float* __restrict__ bias, _Float16* __restrict__ C,
    const int K, const int rowmode, const int three)
{
  __shared__ char smem[32768];   // [Ah|Wh|Wl|Al] x 8 tiles x 64 lanes x 16B
  const int tid = threadIdx.x, lane = tid & 63, wid = tid >> 6;
  const int bn = blockIdx.x, bm = blockIdx.y;
  const int nslot = three ? 8 : 6;

  const u16* gptr[8];
  #pragma unroll
  for (int i = 0; i < 8; ++i){
    const int s = i*256 + tid;                       // staging slot
    const int mat = s >> 9, tile = (s >> 6) & 7, rr = s & 15, quad = (s >> 4) & 3;
    if (mat == 0 || mat == 3){
      const long row = (long)bm*128 + tile*16 + rr;
      const long ro = rowmode ? ((row >> 10)*1025 + (row & 1023) + 1)*512 : row*(long)K;
      gptr[i] = ((mat == 0) ? Ahi : Alo) + ro + quad*8;
    } else {
      const long row = (long)bn*128 + tile*16 + rr;
      gptr[i] = ((mat == 1) ? Whi : Wlo) + row*(long)K + quad*8;
    }
  }

  f32x4 acc[4][4];
  #pragma unroll
  for (int a = 0; a < 4; ++a)
    #pragma unroll
    for (int b = 0; b < 4; ++b) acc[a][b] = (f32x4){0.f,0.f,0.f,0.f};

  const int mh = wid & 1, nh = wid >> 1;

  for (int kk = 0; kk < K; kk += 32){
    __syncthreads();
    #pragma unroll
    for (int i = 0; i < 8; ++i){
      if (i < nslot)
        GLD_LDS16(gptr[i] + kk, &smem[i*4096 + wid*1024]);
    }
    __syncthreads();             // vmcnt drained before barrier -> LDS valid
    bf16x8 ah[4], wh_[4], wl_[4], al[4];
    #pragma unroll
    for (int xi = 0; xi < 4; ++xi){
      const int at = mh*4 + xi, wt = nh*4 + xi;
      ah[xi]  = *(const bf16x8*)(&smem[(at*64 + lane)*16]);
      wh_[xi] = *(const bf16x8*)(&smem[8192  + (wt*64 + lane)*16]);
      wl_[xi] = *(const bf16x8*)(&smem[16384 + (wt*64 + lane)*16]);
    }
    if (three){
      #pragma unroll
      for (int xi = 0; xi < 4; ++xi)
        al[xi] = *(const bf16x8*)(&smem[24576 + ((mh*4 + xi)*64 + lane)*16]);
    }
    #pragma unroll
    for (int mi = 0; mi < 4; ++mi)
      #pragma unroll
      for (int ni = 0; ni < 4; ++ni){
        acc[mi][ni] = __builtin_amdgcn_mfma_f32_16x16x32_bf16(ah[mi], wh_[ni], acc[mi][ni], 0,0,0);
        acc[mi][ni] = __builtin_amdgcn_mfma_f32_16x16x32_bf16(ah[mi], wl_[ni], acc[mi][ni], 0,0,0);
        if (three)
          acc[mi][ni] = __builtin_amdgcn_mfma_f32_16x16x32_bf16(al[mi], wh_[ni], acc[mi][ni], 0,0,0);
      }
  }

  // C/D layout: row m = (lane>>4)*4 + r, col n = lane&15
  const long mbase = (long)bm*128 + mh*64 + (lane >> 4)*4;
  const int  nb    = bn*128 + nh*64 + (lane & 15);
  #pragma unroll
  for (int ni = 0; ni < 4; ++ni){
    const float bv = bias[nb + ni*16];
    #pragma unroll
    for (int mi = 0; mi < 4; ++mi)
      #pragma unroll
      for (int r = 0; r < 4; ++r)
        C[(mbase + mi*16 + r)*2048 + nb + ni*16] = (_Float16)(acc[mi][ni][r] + bv);
  }
}

// --------------------------------------------------- persistent LSTM layer
// grid = 32 blocks (block j owns o-slice [16j,16j+16), all 4 gates, all 32 b)
// wave w = gate w; its 16 rows of Wh (hi+lo) live in 128 VGPRs for all steps.
// Per step: prefetch xp[t]; poll 32 agent-scope flags for h_{t-1}; stage h_hi
// into packed A-frag LDS via global_load_lds; 2-term MFMA; cell update in
// fp32 (c resident in registers); write h_t hi (+ lo into 4-slot ring, only
// consumed by fc at the final step of layer 1); release + flag.
__global__ __launch_bounds__(256, 1) void lstm_layer(
    const _Float16* __restrict__ xp,             // [32768][2048] = [(b,t)][(g,o)]
    const u16* __restrict__ Whi, const u16* __restrict__ Wlo,   // [2048][512]
    u16* __restrict__ hhi, u16* __restrict__ hlo,
    uint32_t* __restrict__ flags, const int layer)
{
  __shared__ char asmem[32768];                  // [c(16)][mt(2)][64][16B]
  __shared__ float gsmem[4][32][16];             // gate exchange
  const int tid = threadIdx.x;
  const int lane = tid & 63;
  const int wid = tid >> 6;                      // gate index (0=G,1=I,2=F,3=O)
  const int j = blockIdx.x;                      // o-slice

  // resident W fragments (B-operand layout: lane holds W[n=lane&15][k=quad*8+jj])
  bf16x8 wfh[16], wfl[16];
  {
    const long nrow = wid*512 + j*16 + (lane & 15);
    const int kq = (lane >> 4) * 8;
    #pragma unroll
    for (int c = 0; c < 16; ++c){
      wfh[c] = *(const bf16x8*)(Whi + nrow*512 + c*32 + kq);
      wfl[c] = *(const bf16x8*)(Wlo + nrow*512 + c*32 + kq);
    }
  }

  // staging offsets (time-invariant part)
  long soff[8];
  #pragma unroll
  for (int i = 0; i < 8; ++i){
    const int grp = wid*8 + i, c = grp >> 1, mt = grp & 1;
    const int b = mt*16 + (lane & 15);
    const int k = c*32 + (lane >> 4)*8;
    soff[i] = (layer == 0) ? ((long)b*524800 + k) : ((long)b*512 + k);
  }

  const int b0 = tid >> 4, oi = tid & 15, b1 = b0 + 16;
  const int og = j*16 + oi;
  const long xq0 = ((long)(b0 << 10))*2048 + j*16 + oi;
  const long xq1 = ((long)(b1 << 10))*2048 + j*16 + oi;
  const long ho0 = (layer == 0) ? ((long)b0*524800 + og) : ((long)b0*512 + og);
  const long ho1 = (layer == 0) ? ((long)b1*524800 + og) : ((long)b1*512 + og);
  const long lo0 = (long)b0*512 + og;            // hlo always ring-addressed
  const long lo1 = (long)b1*512 + og;

  float c0 = 0.f, c1 = 0.f;

  for (int t = 0; t < TSEQ; ++t){
    // xp prefetch (flag-independent: flies during the wait)
    float xv0[4], xv1[4];
    {
      const long base0 = xq0 + (long)t*2048, base1 = xq1 + (long)t*2048;
      #pragma unroll
      for (int g = 0; g < 4; ++g){
        xv0[g] = (float)xp[base0 + g*512];
        xv1[g] = (float)xp[base1 + g*512];
      }
    }
    if (t > 0){
      if (tid < 32){
        const uint32_t* f = &flags[(t-1)*32 + tid];
        while (__hip_atomic_load(f, __ATOMIC_RELAXED, __HIP_MEMORY_SCOPE_AGENT) == 0u){}
      }
      __syncthreads();
      __builtin_amdgcn_fence(__ATOMIC_ACQUIRE, "agent");
    }
    // stage h_{t-1} (hi) into packed A-fragment layout
    {
      const long tterm = (layer == 0) ? (long)t*512 : (long)((t+3)&3)*16384;
      #pragma unroll
      for (int i = 0; i < 8; ++i){
        const int grp = wid*8 + i;
        GLD_LDS16(hhi + soff[i] + tterm, &asmem[grp*1024]);
      }
    }
    __syncthreads();

    f32x4 acc0 = {0.f,0.f,0.f,0.f}, acc1 = {0.f,0.f,0.f,0.f};
    #pragma unroll
    for (int c = 0; c < 16; ++c){
      bf16x8 a0 = *(const bf16x8*)(&asmem[((c*2 + 0)*64 + lane)*16]);
      bf16x8 a1 = *(const bf16x8*)(&asmem[((c*2 + 1)*64 + lane)*16]);
      acc0 = __builtin_amdgcn_mfma_f32_16x16x32_bf16(a0, wfh[c], acc0, 0,0,0);
      acc1 = __builtin_amdgcn_mfma_f32_16x16x32_bf16(a1, wfh[c], acc1, 0,0,0);
      acc0 = __builtin_amdgcn_mfma_f32_16x16x32_bf16(a0, wfl[c], acc0, 0,0,0);
      acc1 = __builtin_amdgcn_mfma_f32_16x16x32_bf16(a1, wfl[c], acc1, 0,0,0);
    }
    {
      const int bq = (lane >> 4) * 4, ci = lane & 15;
      #pragma unroll
      for (int r = 0; r < 4; ++r){
        gsmem[wid][bq + r][ci]      = acc0[r];
        gsmem[wid][16 + bq + r][ci] = acc1[r];
      }
    }
    __syncthreads();
    {
      const long hterm = (layer == 0) ? (long)(t+1)*512 : (long)(t&3)*16384;
      const long lterm = (long)(t&3)*16384;
      float gg = ftanh_(gsmem[0][b0][oi] + xv0[0]);
      float ii = fsig (gsmem[1][b0][oi] + xv0[1]);
      float ff = fsig (gsmem[2][b0][oi] + xv0[2]);
      float oo = fsig (gsmem[3][b0][oi] + xv0[3]);
      c0 = ff*c0 + ii*gg;
      const float h0v = oo * ftanh_(c0);
      gg = ftanh_(gsmem[0][b1][oi] + xv1[0]);
      ii = fsig (gsmem[1][b1][oi] + xv1[1]);
      ff = fsig (gsmem[2][b1][oi] + xv1[2]);
      oo = fsig (gsmem[3][b1][oi] + xv1[3]);
      c1 = ff*c1 + ii*gg;
      const float h1v = oo * ftanh_(c1);
      const u16 h0h = f2bf(h0v), h0l = f2bf(h0v - bf2f(h0h));
      const u16 h1h = f2bf(h1v), h1l = f2bf(h1v - bf2f(h1h));
      hhi[ho0 + hterm] = h0h;  hlo[lo0 + lterm] = h0l;
      hhi[ho1 + hterm] = h1h;  hlo[lo1 + lterm] = h1l;
    }
    __builtin_amdgcn_fence(__ATOMIC_RELEASE, "agent");
    __syncthreads();
    if (tid == 0)
      __hip_atomic_store(&flags[t*32 + j], 1u, __ATOMIC_RELEASE, __HIP_MEMORY_SCOPE_AGENT);
  }
}

// ------------------------------------------------------------------- FC out
__global__ void fc_kernel(const u16* __restrict__ ringh, const u16* __restrict__ ringl,
                          const float* __restrict__ fcW, const float* __restrict__ fcb,
                          float* __restrict__ out)
{
  __shared__ float hbuf[512];
  const int b = blockIdx.x, tid = threadIdx.x;
  for (int i = tid; i < 512; i += 256)
    hbuf[i] = bf2f(ringh[3*16384 + b*512 + i]) + bf2f(ringl[3*16384 + b*512 + i]);
  __syncthreads();
  float acc = fcb[tid];
  const float4* w4 = (const float4*)(fcW + tid*512);
  #pragma unroll 8
  for (int k = 0; k < 128; ++k){
    const float4 w = w4[k];
    acc += hbuf[4*k]*w.x + hbuf[4*k+1]*w.y + hbuf[4*k+2]*w.z + hbuf[4*k+3]*w.w;
  }
  out[b*256 + tid] = acc;
}

// ---------------------------------------------------------------- launcher
extern "C" void kernel_launch(void* const* d_in, const int* in_sizes, int n_in,
                              void* d_out, int out_size, void* d_ws, size_t ws_size,
                              hipStream_t stream)
{
  const float* x   = (const float*)d_in[0];
  const float* Wx0 = (const float*)d_in[1];
  const float* bx0 = (const float*)d_in[2];
  const float* Wh0 = (const float*)d_in[3];
  const float* bh0 = (const float*)d_in[4];
  const float* Wx1 = (const float*)d_in[5];
  const float* bx1 = (const float*)d_in[6];
  const float* Wh1 = (const float*)d_in[7];
  const float* bh1 = (const float*)d_in[8];
  const float* fcW = (const float*)d_in[9];
  const float* fcb = (const float*)d_in[10];

  char* ws = (char*)d_ws;
  size_t off = 0;
  auto take = [&](size_t sz){ void* p = ws + off; off += sz; return p; };
  _Float16* xp   = (_Float16*)take((size_t)32768*2048*2); // 128 MiB, both layers
  u16*   hs0h    = (u16*)take((size_t)32*1025*512*2);     // layer0 h, slot t+1 (slot0 = zeros)
  u16*   xh      = (u16*)take((size_t)8388608*2);
  u16*   xl      = (u16*)take((size_t)8388608*2);
  u16*   wx0h    = (u16*)take((size_t)524288*2);
  u16*   wx0l    = (u16*)take((size_t)524288*2);
  u16*   wh0h    = (u16*)take((size_t)1048576*2);
  u16*   wh0l    = (u16*)take((size_t)1048576*2);
  u16*   wx1h    = (u16*)take((size_t)1048576*2);
  u16*   wx1l    = (u16*)take((size_t)1048576*2);
  u16*   wh1h    = (u16*)take((size_t)1048576*2);
  u16*   wh1l    = (u16*)take((size_t)1048576*2);
  u16*   ringh   = (u16*)take((size_t)4*32*512*2);        // layer1 h ring (+layer0 hlo sink)
  u16*   ringl   = (u16*)take((size_t)4*32*512*2);
  float* bs0     = (float*)take(2048*4);
  float* bs1     = (float*)take(2048*4);
  uint32_t* flags = (uint32_t*)take((size_t)2*32768*4);   // [layer][t][block]
  (void)in_sizes; (void)n_in; (void)out_size; (void)ws_size;

  (void)hipMemsetAsync(flags, 0, (size_t)2*32768*4, stream);

  split_f32<<<4096,256,0,stream>>>(x,   xh,   xl,   8388608);
  split_f32<<<1024,256,0,stream>>>(Wx0, wx0h, wx0l, 524288);
  split_f32<<<2048,256,0,stream>>>(Wh0, wh0h, wh0l, 1048576);
  split_f32<<<2048,256,0,stream>>>(Wx1, wx1h, wx1l, 1048576);
  split_f32<<<2048,256,0,stream>>>(Wh1, wh1h, wh1l, 1048576);
  vec_add<<<8,256,0,stream>>>(bx0, bh0, bs0, 2048);
  vec_add<<<8,256,0,stream>>>(bx1, bh1, bs1, 2048);
  init_state<<<64,256,0,stream>>>(hs0h, ringh, ringl);

  dim3 gg(16, 256);
  // xproj0 = x @ Wx0^T + (bx0+bh0), 3-term split-bf16
  gemm_split<<<gg,256,0,stream>>>(xh, xl, wx0h, wx0l, bs0, xp, 256, 0, 1);
  lstm_layer<<<32,256,0,stream>>>(xp, wh0h, wh0l, hs0h, ringl, flags, 0);
  // xproj1 = hs0 @ Wx1^T + (bx1+bh1), 2-term (uses only A-hi)
  gemm_split<<<gg,256,0,stream>>>(hs0h, (const u16*)hs0h, wx1h, wx1l, bs1, xp, 512, 1, 0);
  lstm_layer<<<32,256,0,stream>>>(xp, wh1h, wh1l, ringh, ringl, flags + 32768, 1);
  fc_kernel<<<32,256,0,stream>>>(ringh, ringl, fcW, fcb, (float*)d_out);
}

// Round 4
// 13968.602 us; speedup vs baseline: 1.1114x; 1.1114x over previous
//
#include <hip/hip_runtime.h>
#include <hip/hip_bf16.h>
#include <stdint.h>

// 2-layer LSTM, B=32 T=1024 D=256 H=512, fc -> 256.
// Split-bf16 MFMA GEMMs for input projections (xp stored fp16); persistent
// weight-stationary recurrence (32 blocks, Wh frags register-resident) with
// FENCE-FREE agent-scope handshake: h passed via relaxed agent atomics
// (write-through to LLC / read-from-LLC), ordering via s_waitcnt vmcnt(0) +
// flag store. No buffer_wbl2 / buffer_inv per step. Workspace ~207 MiB.

typedef __attribute__((ext_vector_type(8))) short bf16x8;
typedef __attribute__((ext_vector_type(4))) float f32x4;
typedef unsigned short u16;

#define TSEQ 1024

static __device__ __forceinline__ float fsig(float x){ return 1.0f/(1.0f+__expf(-x)); }
static __device__ __forceinline__ float ftanh_(float x){ return 2.0f/(1.0f+__expf(-2.0f*x)) - 1.0f; }
static __device__ __forceinline__ u16 f2bf(float v){
  __hip_bfloat16 b = __float2bfloat16(v);
  return *reinterpret_cast<u16*>(&b);
}
static __device__ __forceinline__ float bf2f(u16 u){
  __hip_bfloat16 b; *reinterpret_cast<u16*>(&b) = u;
  return __bfloat162float(b);
}

// async global->LDS, 16B per lane; LDS dest = uniform base + lane*16
#define GLD_LDS16(g, l) \
  __builtin_amdgcn_global_load_lds((const __attribute__((address_space(1))) uint32_t*)(g), \
                                   (__attribute__((address_space(3))) uint32_t*)(l), 16, 0, 0)

// ---------------------------------------------------------------- utilities
__global__ void split_f32(const float* __restrict__ src, u16* __restrict__ hi,
                          u16* __restrict__ lo, const int n)
{
  for (int i = blockIdx.x*blockDim.x + threadIdx.x; i < n; i += gridDim.x*blockDim.x){
    const float v = src[i];
    const u16 h = f2bf(v);
    hi[i] = h;
    lo[i] = f2bf(v - bf2f(h));
  }
}

__global__ void vec_add(const float* __restrict__ a, const float* __restrict__ b,
                        float* __restrict__ c, const int n)
{
  const int i = blockIdx.x*blockDim.x + threadIdx.x;
  if (i < n) c[i] = a[i] + b[i];
}

// zero h_{-1}: layer0 hs0 slot 0, layer1 ring slot 3 (u32-packed buffers)
__global__ void init_state(uint32_t* hs0, uint32_t* ring)
{
  const int i = blockIdx.x*256 + threadIdx.x;       // 8192 = 32*256
  const int b = i >> 8, o2 = i & 255;
  hs0[(long)b*262400 + o2] = 0;                     // (b*1025 + 0)*256 + o2
  ring[3*8192 + i] = 0;
}

// ------------------------------------------------------ split-bf16 MFMA GEMM
// C[m][n] = sum_k A[m][k]*W[n][k] + bias[n],  M=32768 N=2048, K in {256,512}
// A = Ahi+Alo, W = Whi+Wlo. three=1: Ah*Wh + Ah*Wl + Al*Wh; three=0: Ah*(Wh+Wl).
// rowmode=1: A rows are hs0 layout [B][T+1][512] at slot t+1 (m = b*1024+t).
// Output C is fp16 (pre-activation values are O(1); fp16 err ~3e-4).
// LDS holds tiles already in packed MFMA-fragment order -> conflict-free b128.
__global__ __launch_bounds__(256, 2) void gemm_split(
    const u16* __restrict__ Ahi, const u16* __restrict__ Alo,
    const u16* __restrict__ Whi, const u16* __restrict__ Wlo,
    const float* __restrict__ bias, _Float16* __restrict__ C,
    const int K, const int rowmode, const int three)
{
  __shared__ char smem[32768];   // [Ah|Wh|Wl|Al] x 8 tiles x 64 lanes x 16B
  const int tid = threadIdx.x, lane = tid & 63, wid = tid >> 6;
  const int bn = blockIdx.x, bm = blockIdx.y;
  const int nslot = three ? 8 : 6;

  const u16* gptr[8];
  #pragma unroll
  for (int i = 0; i < 8; ++i){
    const int s = i*256 + tid;                       // staging slot
    const int mat = s >> 9, tile = (s >> 6) & 7, rr = s & 15, quad = (s >> 4) & 3;
    if (mat == 0 || mat == 3){
      const long row = (long)bm*128 + tile*16 + rr;
      const long ro = rowmode ? ((row >> 10)*1025 + (row & 1023) + 1)*512 : row*(long)K;
      gptr[i] = ((mat == 0) ? Ahi : Alo) + ro + quad*8;
    } else {
      const long row = (long)bn*128 + tile*16 + rr;
      gptr[i] = ((mat == 1) ? Whi : Wlo) + row*(long)K + quad*8;
    }
  }

  f32x4 acc[4][4];
  #pragma unroll
  for (int a = 0; a < 4; ++a)
    #pragma unroll
    for (int b = 0; b < 4; ++b) acc[a][b] = (f32x4){0.f,0.f,0.f,0.f};

  const int mh = wid & 1, nh = wid >> 1;

  for (int kk = 0; kk < K; kk += 32){
    __syncthreads();
    #pragma unroll
    for (int i = 0; i < 8; ++i){
      if (i < nslot)
        GLD_LDS16(gptr[i] + kk, &smem[i*4096 + wid*1024]);
    }
    __syncthreads();             // vmcnt drained before barrier -> LDS valid
    bf16x8 ah[4], wh_[4], wl_[4], al[4];
    #pragma unroll
    for (int xi = 0; xi < 4; ++xi){
      const int at = mh*4 + xi, wt = nh*4 + xi;
      ah[xi]  = *(const bf16x8*)(&smem[(at*64 + lane)*16]);
      wh_[xi] = *(const bf16x8*)(&smem[8192  + (wt*64 + lane)*16]);
      wl_[xi] = *(const bf16x8*)(&smem[16384 + (wt*64 + lane)*16]);
    }
    if (three){
      #pragma unroll
      for (int xi = 0; xi < 4; ++xi)
        al[xi] = *(const bf16x8*)(&smem[24576 + ((mh*4 + xi)*64 + lane)*16]);
    }
    #pragma unroll
    for (int mi = 0; mi < 4; ++mi)
      #pragma unroll
      for (int ni = 0; ni < 4; ++ni){
        acc[mi][ni] = __builtin_amdgcn_mfma_f32_16x16x32_bf16(ah[mi], wh_[ni], acc[mi][ni], 0,0,0);
        acc[mi][ni] = __builtin_amdgcn_mfma_f32_16x16x32_bf16(ah[mi], wl_[ni], acc[mi][ni], 0,0,0);
        if (three)
          acc[mi][ni] = __builtin_amdgcn_mfma_f32_16x16x32_bf16(al[mi], wh_[ni], acc[mi][ni], 0,0,0);
      }
  }

  // C/D layout: row m = (lane>>4)*4 + r, col n = lane&15
  const long mbase = (long)bm*128 + mh*64 + (lane >> 4)*4;
  const int  nb    = bn*128 + nh*64 + (lane & 15);
  #pragma unroll
  for (int ni = 0; ni < 4; ++ni){
    const float bv = bias[nb + ni*16];
    #pragma unroll
    for (int mi = 0; mi < 4; ++mi)
      #pragma unroll
      for (int r = 0; r < 4; ++r)
        C[(mbase + mi*16 + r)*2048 + nb + ni*16] = (_Float16)(acc[mi][ni][r] + bv);
  }
}

// --------------------------------------------------- persistent LSTM layer
// grid = 32 blocks (block j owns o-slice [16j,16j+16), all 4 gates, all 32 b)
// wave w = gate w; its 16 rows of Wh (hi+lo) stay register-resident.
// Per step: prefetch xp[t]; poll 32 flags (relaxed agent loads, LLC);
// atomic-load h_{t-1} (u32-packed) into regs -> ds_write_b128 into packed
// A-frag LDS; 2-term MFMA; gates in fp32; h_t stored via relaxed agent
// atomic u32 stores; s_waitcnt vmcnt(0); barrier; flag store. NO fences.
__global__ __launch_bounds__(256, 1) void lstm_layer(
    const _Float16* __restrict__ xp,             // [32768][2048] = [(b,t)][(g,o)]
    const u16* __restrict__ Whi, const u16* __restrict__ Wlo,   // [2048][512]
    uint32_t* __restrict__ hbuf,  // layer0: [b][1025][256]u32 ; layer1: ring [4][32][256]u32
    float* __restrict__ hfin,     // [32][512] final h fp32 (layer 1 only)
    uint32_t* __restrict__ flags, const int layer)
{
  __shared__ char asmem[32768];                  // [c(16)][mt(2)][64][16B]
  __shared__ float gsmem[4][32][16];             // gate exchange
  const int tid = threadIdx.x;
  const int lane = tid & 63;
  const int wid = tid >> 6;                      // gate index (0=G,1=I,2=F,3=O)
  const int j = blockIdx.x;                      // o-slice

  // resident W fragments (B-operand layout: lane holds W[n=lane&15][k=quad*8+jj])
  bf16x8 wfh[16], wfl[16];
  {
    const long nrow = wid*512 + j*16 + (lane & 15);
    const int kq = (lane >> 4) * 8;
    #pragma unroll
    for (int c = 0; c < 16; ++c){
      wfh[c] = *(const bf16x8*)(Whi + nrow*512 + c*32 + kq);
      wfl[c] = *(const bf16x8*)(Wlo + nrow*512 + c*32 + kq);
    }
  }

  // staging source offsets in u32 units (time-invariant part)
  int soff32[8];
  #pragma unroll
  for (int i = 0; i < 8; ++i){
    const int grp = wid*8 + i, c = grp >> 1, mt = grp & 1;
    const int b = mt*16 + (lane & 15);
    const int k = c*32 + (lane >> 4)*8;          // u16 index within row
    soff32[i] = (layer == 0) ? (b*262400 + (k >> 1)) : (b*256 + (k >> 1));
  }

  const int b0 = tid >> 4, oi = tid & 15, b1 = b0 + 16;
  const int og = j*16 + oi;
  const long xq0 = ((long)(b0 << 10))*2048 + j*16 + oi;
  const long xq1 = ((long)(b1 << 10))*2048 + j*16 + oi;

  float c0 = 0.f, c1 = 0.f;

  for (int t = 0; t < TSEQ; ++t){
    // xp prefetch (flag-independent: flies during the wait)
    float xv0[4], xv1[4];
    {
      const long base0 = xq0 + (long)t*2048, base1 = xq1 + (long)t*2048;
      #pragma unroll
      for (int g = 0; g < 4; ++g){
        xv0[g] = (float)xp[base0 + g*512];
        xv1[g] = (float)xp[base1 + g*512];
      }
    }
    if (t > 0){
      if (tid < 32){
        const uint32_t* f = &flags[(t-1)*32 + tid];
        while (__hip_atomic_load(f, __ATOMIC_RELAXED, __HIP_MEMORY_SCOPE_AGENT) == 0u){}
      }
      __syncthreads();           // all h_{t-1} committed to LLC before loads below
    }
    // load h_{t-1} from LLC (relaxed agent atomics) -> packed A-frag LDS
    {
      const int tterm32 = (layer == 0) ? t*256 : ((t+3)&3)*8192;
      uint32_t hv[32];
      #pragma unroll
      for (int i = 0; i < 8; ++i){
        const uint32_t* src = hbuf + soff32[i] + tterm32;
        #pragma unroll
        for (int q = 0; q < 4; ++q)
          hv[i*4+q] = __hip_atomic_load(src + q, __ATOMIC_RELAXED, __HIP_MEMORY_SCOPE_AGENT);
      }
      #pragma unroll
      for (int i = 0; i < 8; ++i){
        const int grp = wid*8 + i;
        uint4 w; w.x = hv[i*4]; w.y = hv[i*4+1]; w.z = hv[i*4+2]; w.w = hv[i*4+3];
        *(uint4*)(&asmem[grp*1024 + lane*16]) = w;
      }
    }
    __syncthreads();

    f32x4 acc0 = {0.f,0.f,0.f,0.f}, acc1 = {0.f,0.f,0.f,0.f};
    #pragma unroll
    for (int c = 0; c < 16; ++c){
      bf16x8 a0 = *(const bf16x8*)(&asmem[((c*2 + 0)*64 + lane)*16]);
      bf16x8 a1 = *(const bf16x8*)(&asmem[((c*2 + 1)*64 + lane)*16]);
      acc0 = __builtin_amdgcn_mfma_f32_16x16x32_bf16(a0, wfh[c], acc0, 0,0,0);
      acc1 = __builtin_amdgcn_mfma_f32_16x16x32_bf16(a1, wfh[c], acc1, 0,0,0);
      acc0 = __builtin_amdgcn_mfma_f32_16x16x32_bf16(a0, wfl[c], acc0, 0,0,0);
      acc1 = __builtin_amdgcn_mfma_f32_16x16x32_bf16(a1, wfl[c], acc1, 0,0,0);
    }
    {
      const int bq = (lane >> 4) * 4, ci = lane & 15;
      #pragma unroll
      for (int r = 0; r < 4; ++r){
        gsmem[wid][bq + r][ci]      = acc0[r];
        gsmem[wid][16 + bq + r][ci] = acc1[r];
      }
    }
    __syncthreads();
    {
      float gg = ftanh_(gsmem[0][b0][oi] + xv0[0]);
      float ii = fsig (gsmem[1][b0][oi] + xv0[1]);
      float ff = fsig (gsmem[2][b0][oi] + xv0[2]);
      float oo = fsig (gsmem[3][b0][oi] + xv0[3]);
      c0 = ff*c0 + ii*gg;
      const float h0v = oo * ftanh_(c0);
      gg = ftanh_(gsmem[0][b1][oi] + xv1[0]);
      ii = fsig (gsmem[1][b1][oi] + xv1[1]);
      ff = fsig (gsmem[2][b1][oi] + xv1[2]);
      oo = fsig (gsmem[3][b1][oi] + xv1[3]);
      c1 = ff*c1 + ii*gg;
      const float h1v = oo * ftanh_(c1);

      if (layer == 1 && t == TSEQ-1){            // fp32 h for the FC
        hfin[b0*512 + og] = h0v;
        hfin[b1*512 + og] = h1v;
      }

      // pack adjacent-o bf16 pair into u32 (even-oi thread stores both b's)
      const u16 h0h = f2bf(h0v), h1h = f2bf(h1v);
      const int p0o = __shfl_xor((int)h0h, 1, 64);
      const int p1o = __shfl_xor((int)h1h, 1, 64);
      if ((oi & 1) == 0){
        const uint32_t p0 = (uint32_t)h0h | ((uint32_t)(p0o & 0xffff) << 16);
        const uint32_t p1 = (uint32_t)h1h | ((uint32_t)(p1o & 0xffff) << 16);
        long d0, d1;
        if (layer == 0){
          d0 = (long)b0*262400 + (long)(t+1)*256 + (og >> 1);
          d1 = (long)b1*262400 + (long)(t+1)*256 + (og >> 1);
        } else {
          d0 = (long)(t&3)*8192 + b0*256 + (og >> 1);
          d1 = (long)(t&3)*8192 + b1*256 + (og >> 1);
        }
        __hip_atomic_store(hbuf + d0, p0, __ATOMIC_RELAXED, __HIP_MEMORY_SCOPE_AGENT);
        __hip_atomic_store(hbuf + d1, p1, __ATOMIC_RELAXED, __HIP_MEMORY_SCOPE_AGENT);
      }
    }
    asm volatile("s_waitcnt vmcnt(0)" ::: "memory");   // h stores acked at LLC
    __syncthreads();
    if (tid == 0)
      __hip_atomic_store(&flags[t*32 + j], 1u, __ATOMIC_RELAXED, __HIP_MEMORY_SCOPE_AGENT);
  }
}

// ------------------------------------------------------------------- FC out
__global__ void fc_kernel(const float* __restrict__ hfin,
                          const float* __restrict__ fcW, const float* __restrict__ fcb,
                          float* __restrict__ out)
{
  __shared__ float hbufs[512];
  const int b = blockIdx.x, tid = threadIdx.x;
  for (int i = tid; i < 512; i += 256)
    hbufs[i] = hfin[b*512 + i];
  __syncthreads();
  float acc = fcb[tid];
  const float4* w4 = (const float4*)(fcW + tid*512);
  #pragma unroll 8
  for (int k = 0; k < 128; ++k){
    const float4 w = w4[k];
    acc += hbufs[4*k]*w.x + hbufs[4*k+1]*w.y + hbufs[4*k+2]*w.z + hbufs[4*k+3]*w.w;
  }
  out[b*256 + tid] = acc;
}

// ---------------------------------------------------------------- launcher
extern "C" void kernel_launch(void* const* d_in, const int* in_sizes, int n_in,
                              void* d_out, int out_size, void* d_ws, size_t ws_size,
                              hipStream_t stream)
{
  const float* x   = (const float*)d_in[0];
  const float* Wx0 = (const float*)d_in[1];
  const float* bx0 = (const float*)d_in[2];
  const float* Wh0 = (const float*)d_in[3];
  const float* bh0 = (const float*)d_in[4];
  const float* Wx1 = (const float*)d_in[5];
  const float* bx1 = (const float*)d_in[6];
  const float* Wh1 = (const float*)d_in[7];
  const float* bh1 = (const float*)d_in[8];
  const float* fcW = (const float*)d_in[9];
  const float* fcb = (const float*)d_in[10];

  char* ws = (char*)d_ws;
  size_t off = 0;
  auto take = [&](size_t sz){ void* p = ws + off; off += sz; return p; };
  _Float16* xp   = (_Float16*)take((size_t)32768*2048*2);  // 128 MiB, both layers
  uint32_t* hs0  = (uint32_t*)take((size_t)32*1025*256*4); // layer0 h hist, u32-packed
  u16*   xh      = (u16*)take((size_t)8388608*2);
  u16*   xl      = (u16*)take((size_t)8388608*2);
  u16*   wx0h    = (u16*)take((size_t)524288*2);
  u16*   wx0l    = (u16*)take((size_t)524288*2);
  u16*   wh0h    = (u16*)take((size_t)1048576*2);
  u16*   wh0l    = (u16*)take((size_t)1048576*2);
  u16*   wx1h    = (u16*)take((size_t)1048576*2);
  u16*   wx1l    = (u16*)take((size_t)1048576*2);
  u16*   wh1h    = (u16*)take((size_t)1048576*2);
  u16*   wh1l    = (u16*)take((size_t)1048576*2);
  uint32_t* ring = (uint32_t*)take((size_t)4*32*256*4);    // layer1 h ring, u32-packed
  float* hfin    = (float*)take((size_t)32*512*4);
  float* bs0     = (float*)take(2048*4);
  float* bs1     = (float*)take(2048*4);
  uint32_t* flags = (uint32_t*)take((size_t)2*32768*4);    // [layer][t][block]
  (void)in_sizes; (void)n_in; (void)out_size; (void)ws_size;

  (void)hipMemsetAsync(flags, 0, (size_t)2*32768*4, stream);

  split_f32<<<4096,256,0,stream>>>(x,   xh,   xl,   8388608);
  split_f32<<<1024,256,0,stream>>>(Wx0, wx0h, wx0l, 524288);
  split_f32<<<2048,256,0,stream>>>(Wh0, wh0h, wh0l, 1048576);
  split_f32<<<2048,256,0,stream>>>(Wx1, wx1h, wx1l, 1048576);
  split_f32<<<2048,256,0,stream>>>(Wh1, wh1h, wh1l, 1048576);
  vec_add<<<8,256,0,stream>>>(bx0, bh0, bs0, 2048);
  vec_add<<<8,256,0,stream>>>(bx1, bh1, bs1, 2048);
  init_state<<<32,256,0,stream>>>(hs0, ring);

  dim3 gg(16, 256);
  // xproj0 = x @ Wx0^T + (bx0+bh0), 3-term split-bf16
  gemm_split<<<gg,256,0,stream>>>(xh, xl, wx0h, wx0l, bs0, xp, 256, 0, 1);
  lstm_layer<<<32,256,0,stream>>>(xp, wh0h, wh0l, hs0, hfin, flags, 0);
  // xproj1 = hs0 @ Wx1^T + (bx1+bh1), 2-term (uses only A-hi; hs0 bytes = u16 layout)
  gemm_split<<<gg,256,0,stream>>>((const u16*)hs0, (const u16*)hs0, wx1h, wx1l, bs1, xp, 512, 1, 0);
  lstm_layer<<<32,256,0,stream>>>(xp, wh1h, wh1l, ring, hfin, flags + 32768, 1);
  fc_kernel<<<32,256,0,stream>>>(hfin, fcW, fcb, (float*)d_out);
}

// Round 5
// 6897.340 us; speedup vs baseline: 2.2509x; 2.0252x over previous
//
#include <hip/hip_runtime.h>
#include <hip/hip_bf16.h>
#include <stdint.h>

// 2-layer LSTM, B=32 T=1024 D=256 H=512, fc -> 256.
// R5: single fused persistent kernel for BOTH layers (64 blocks; layer-1
// blocks keep Wh1+Wx1 resident and compute Wx1*h0[t] on the fly -> xproj1
// GEMM eliminated; layers overlap in a wavefront pipeline). h restage uses
// pipelined inline-asm global_load_dwordx4 sc0 sc1 (LLC-coherent) instead of
// 32 serial atomic dword loads; per-step sync via ONE counter (atomicAdd +
// single-address poll). Workspace ~216 MiB.

typedef __attribute__((ext_vector_type(8))) short bf16x8;
typedef __attribute__((ext_vector_type(4))) float f32x4;
typedef __attribute__((ext_vector_type(4))) unsigned int u32x4;
typedef unsigned short u16;

#define TSEQ 1024

static __device__ __forceinline__ float fsig(float x){ return 1.0f/(1.0f+__expf(-x)); }
static __device__ __forceinline__ float ftanh_(float x){ return 2.0f/(1.0f+__expf(-2.0f*x)) - 1.0f; }
static __device__ __forceinline__ u16 f2bf(float v){
  __hip_bfloat16 b = __float2bfloat16(v);
  return *reinterpret_cast<u16*>(&b);
}
static __device__ __forceinline__ float bf2f(u16 u){
  __hip_bfloat16 b; *reinterpret_cast<u16*>(&b) = u;
  return __bfloat162float(b);
}

// async global->LDS, 16B per lane (GEMM staging)
#define GLD_LDS16(g, l) \
  __builtin_amdgcn_global_load_lds((const __attribute__((address_space(1))) uint32_t*)(g), \
                                   (__attribute__((address_space(3))) uint32_t*)(l), 16, 0, 0)

// 8 pipelined LLC-coherent 16B loads + one drain (h restage)
#define COH_LOAD8(p0,p1,p2,p3,p4,p5,p6,p7, r0,r1,r2,r3,r4,r5,r6,r7)   \
  asm volatile(                                                        \
    "global_load_dwordx4 %0, %8, off sc0 sc1\n\t"                      \
    "global_load_dwordx4 %1, %9, off sc0 sc1\n\t"                      \
    "global_load_dwordx4 %2, %10, off sc0 sc1\n\t"                     \
    "global_load_dwordx4 %3, %11, off sc0 sc1\n\t"                     \
    "global_load_dwordx4 %4, %12, off sc0 sc1\n\t"                     \
    "global_load_dwordx4 %5, %13, off sc0 sc1\n\t"                     \
    "global_load_dwordx4 %6, %14, off sc0 sc1\n\t"                     \
    "global_load_dwordx4 %7, %15, off sc0 sc1\n\t"                     \
    "s_waitcnt vmcnt(0)"                                               \
    : "=&v"(r0), "=&v"(r1), "=&v"(r2), "=&v"(r3),                      \
      "=&v"(r4), "=&v"(r5), "=&v"(r6), "=&v"(r7)                       \
    : "v"(p0), "v"(p1), "v"(p2), "v"(p3),                              \
      "v"(p4), "v"(p5), "v"(p6), "v"(p7)                               \
    : "memory")

// single-address counter poll (wave-broadcast LLC read)
static __device__ __forceinline__ void poll32(const uint32_t* c){
  uint32_t v;
  do {
    asm volatile("global_load_dword %0, %1, off sc0 sc1\n\ts_waitcnt vmcnt(0)"
                 : "=v"(v) : "v"(c) : "memory");
  } while (v < 32u);
}

// ---------------------------------------------------------------- utilities
__global__ void split_f32(const float* __restrict__ src, u16* __restrict__ hi,
                          u16* __restrict__ lo, const int n)
{
  for (int i = blockIdx.x*blockDim.x + threadIdx.x; i < n; i += gridDim.x*blockDim.x){
    const float v = src[i];
    const u16 h = f2bf(v);
    hi[i] = h;
    lo[i] = f2bf(v - bf2f(h));
  }
}

__global__ void vec_add(const float* __restrict__ a, const float* __restrict__ b,
                        float* __restrict__ c, const int n)
{
  const int i = blockIdx.x*blockDim.x + threadIdx.x;
  if (i < n) c[i] = a[i] + b[i];
}

// zero h_{-1}: layer0 hbuf0 slot 0, layer1 ring slot 3 (u32-packed)
__global__ void init_state(uint32_t* hbuf0, uint32_t* ring)
{
  const int i = blockIdx.x*256 + threadIdx.x;       // 8192 = 32*256
  const int b = i >> 8, o2 = i & 255;
  hbuf0[(long)b*262400 + o2] = 0;                   // (b*1025 + 0)*256 + o2
  ring[3*8192 + i] = 0;
}

// ------------------------------------------------------ split-bf16 MFMA GEMM
// xproj0 only: C[m][n] = sum_k A[m][k]*W[n][k] + bias[n], M=32768 N=2048 K=256
// 3-term split-bf16: Ah*Wh + Ah*Wl + Al*Wh. Output fp16.
__global__ __launch_bounds__(256, 2) void gemm_split(
    const u16* __restrict__ Ahi, const u16* __restrict__ Alo,
    const u16* __restrict__ Whi, const u16* __restrict__ Wlo,
    const float* __restrict__ bias, _Float16* __restrict__ C,
    const int K)
{
  __shared__ char smem[32768];   // [Ah|Wh|Wl|Al] x 8 tiles x 64 lanes x 16B
  const int tid = threadIdx.x, lane = tid & 63, wid = tid >> 6;
  const int bn = blockIdx.x, bm = blockIdx.y;

  const u16* gptr[8];
  #pragma unroll
  for (int i = 0; i < 8; ++i){
    const int s = i*256 + tid;                       // staging slot
    const int mat = s >> 9, tile = (s >> 6) & 7, rr = s & 15, quad = (s >> 4) & 3;
    if (mat == 0 || mat == 3){
      const long row = (long)bm*128 + tile*16 + rr;
      gptr[i] = ((mat == 0) ? Ahi : Alo) + row*(long)K + quad*8;
    } else {
      const long row = (long)bn*128 + tile*16 + rr;
      gptr[i] = ((mat == 1) ? Whi : Wlo) + row*(long)K + quad*8;
    }
  }

  f32x4 acc[4][4];
  #pragma unroll
  for (int a = 0; a < 4; ++a)
    #pragma unroll
    for (int b = 0; b < 4; ++b) acc[a][b] = (f32x4){0.f,0.f,0.f,0.f};

  const int mh = wid & 1, nh = wid >> 1;

  for (int kk = 0; kk < K; kk += 32){
    __syncthreads();
    #pragma unroll
    for (int i = 0; i < 8; ++i)
      GLD_LDS16(gptr[i] + kk, &smem[i*4096 + wid*1024]);
    __syncthreads();
    bf16x8 ah[4], wh_[4], wl_[4], al[4];
    #pragma unroll
    for (int xi = 0; xi < 4; ++xi){
      const int at = mh*4 + xi, wt = nh*4 + xi;
      ah[xi]  = *(const bf16x8*)(&smem[(at*64 + lane)*16]);
      wh_[xi] = *(const bf16x8*)(&smem[8192  + (wt*64 + lane)*16]);
      wl_[xi] = *(const bf16x8*)(&smem[16384 + (wt*64 + lane)*16]);
      al[xi]  = *(const bf16x8*)(&smem[24576 + (at*64 + lane)*16]);
    }
    #pragma unroll
    for (int mi = 0; mi < 4; ++mi)
      #pragma unroll
      for (int ni = 0; ni < 4; ++ni){
        acc[mi][ni] = __builtin_amdgcn_mfma_f32_16x16x32_bf16(ah[mi], wh_[ni], acc[mi][ni], 0,0,0);
        acc[mi][ni] = __builtin_amdgcn_mfma_f32_16x16x32_bf16(ah[mi], wl_[ni], acc[mi][ni], 0,0,0);
        acc[mi][ni] = __builtin_amdgcn_mfma_f32_16x16x32_bf16(al[mi], wh_[ni], acc[mi][ni], 0,0,0);
      }
  }

  const long mbase = (long)bm*128 + mh*64 + (lane >> 4)*4;
  const int  nb    = bn*128 + nh*64 + (lane & 15);
  #pragma unroll
  for (int ni = 0; ni < 4; ++ni){
    const float bv = bias[nb + ni*16];
    #pragma unroll
    for (int mi = 0; mi < 4; ++mi)
      #pragma unroll
      for (int r = 0; r < 4; ++r)
        C[(mbase + mi*16 + r)*2048 + nb + ni*16] = (_Float16)(acc[mi][ni][r] + bv);
  }
}

// -------------------------------------------- fused persistent 2-layer LSTM
// 64 blocks. Blocks 0-31: layer 0 (xp + Wh0*h0[t-1]); publish h0[t] to
// hbuf0[b][t+1][256]u32, cntA[t]++. Blocks 32-63: layer 1 (bs1 + Wx1*h0[t]
// + Wh1*h1[t-1]); wait cntB[t-1] then cntA[t]; publish h1[t] ring, cntB[t]++.
__global__ __launch_bounds__(256, 1) void lstm_fused(
    const _Float16* __restrict__ xp,             // [32768][2048] = [(b,t)][(g,o)]
    const u16* __restrict__ Wh0hi, const u16* __restrict__ Wh0lo,
    const u16* __restrict__ Wh1hi, const u16* __restrict__ Wh1lo,
    const u16* __restrict__ Wx1hi, const u16* __restrict__ Wx1lo,
    const float* __restrict__ bs1,
    uint32_t* __restrict__ hbuf0,                // [32][1025][256] u32
    uint32_t* __restrict__ ring,                 // [4][32][256] u32
    float* __restrict__ hfin,                    // [32][512] fp32
    uint32_t* __restrict__ cntA, uint32_t* __restrict__ cntB)
{
  __shared__ char asmem0[32768];                 // A-frag image (h0 / own h)
  __shared__ char asmem1[32768];                 // A-frag image (h1, layer1)
  __shared__ float gsmem[4][32][16];             // gate exchange
  const int tid = threadIdx.x;
  const int lane = tid & 63;
  const int wid = tid >> 6;                      // gate index (0=G,1=I,2=F,3=O)
  const int role = blockIdx.x >> 5;              // 0 = layer0, 1 = layer1
  const int j = blockIdx.x & 31;                 // o-slice

  // staging offsets (u32 units, time-invariant): grp=wid*8+i
  int soff0[8], soffR[8];
  #pragma unroll
  for (int i = 0; i < 8; ++i){
    const int grp = wid*8 + i, c = grp >> 1, mt = grp & 1;
    const int b = mt*16 + (lane & 15);
    const int k = c*32 + (lane >> 4)*8;
    soff0[i] = b*262400 + (k >> 1);
    soffR[i] = b*256 + (k >> 1);
  }

  const int b0 = tid >> 4, oi = tid & 15, b1 = b0 + 16;
  const int og = j*16 + oi;
  float c0 = 0.f, c1 = 0.f;

  if (role == 0){
    // ---- layer 0 ----
    bf16x8 wfh[16], wfl[16];
    {
      const long nrow = wid*512 + j*16 + (lane & 15);
      const int kq = (lane >> 4) * 8;
      #pragma unroll
      for (int c = 0; c < 16; ++c){
        wfh[c] = *(const bf16x8*)(Wh0hi + nrow*512 + c*32 + kq);
        wfl[c] = *(const bf16x8*)(Wh0lo + nrow*512 + c*32 + kq);
      }
    }
    const long xq0 = ((long)(b0 << 10))*2048 + j*16 + oi;
    const long xq1 = ((long)(b1 << 10))*2048 + j*16 + oi;

    for (int t = 0; t < TSEQ; ++t){
      float xv0[4], xv1[4];
      {
        const long base0 = xq0 + (long)t*2048, base1 = xq1 + (long)t*2048;
        #pragma unroll
        for (int g = 0; g < 4; ++g){
          xv0[g] = (float)xp[base0 + g*512];
          xv1[g] = (float)xp[base1 + g*512];
        }
      }
      if (t > 0){
        if (tid < 64) poll32(cntA + (t-1));
        __syncthreads();
      }
      { // stage h0[t-1] (slot t) -> asmem0
        const int tt = t*256;
        u32x4 r0,r1,r2,r3,r4,r5,r6,r7;
        COH_LOAD8(hbuf0+soff0[0]+tt, hbuf0+soff0[1]+tt, hbuf0+soff0[2]+tt, hbuf0+soff0[3]+tt,
                  hbuf0+soff0[4]+tt, hbuf0+soff0[5]+tt, hbuf0+soff0[6]+tt, hbuf0+soff0[7]+tt,
                  r0,r1,r2,r3,r4,r5,r6,r7);
        char* base = &asmem0[(wid*8)*1024 + lane*16];
        *(u32x4*)(base+0*1024)=r0; *(u32x4*)(base+1*1024)=r1;
        *(u32x4*)(base+2*1024)=r2; *(u32x4*)(base+3*1024)=r3;
        *(u32x4*)(base+4*1024)=r4; *(u32x4*)(base+5*1024)=r5;
        *(u32x4*)(base+6*1024)=r6; *(u32x4*)(base+7*1024)=r7;
      }
      __syncthreads();

      f32x4 acc0 = {0.f,0.f,0.f,0.f}, acc1 = {0.f,0.f,0.f,0.f};
      #pragma unroll
      for (int c = 0; c < 16; ++c){
        bf16x8 a0 = *(const bf16x8*)(&asmem0[((c*2 + 0)*64 + lane)*16]);
        bf16x8 a1 = *(const bf16x8*)(&asmem0[((c*2 + 1)*64 + lane)*16]);
        acc0 = __builtin_amdgcn_mfma_f32_16x16x32_bf16(a0, wfh[c], acc0, 0,0,0);
        acc1 = __builtin_amdgcn_mfma_f32_16x16x32_bf16(a1, wfh[c], acc1, 0,0,0);
        acc0 = __builtin_amdgcn_mfma_f32_16x16x32_bf16(a0, wfl[c], acc0, 0,0,0);
        acc1 = __builtin_amdgcn_mfma_f32_16x16x32_bf16(a1, wfl[c], acc1, 0,0,0);
      }
      {
        const int bq = (lane >> 4) * 4, ci = lane & 15;
        #pragma unroll
        for (int r = 0; r < 4; ++r){
          gsmem[wid][bq + r][ci]      = acc0[r];
          gsmem[wid][16 + bq + r][ci] = acc1[r];
        }
      }
      __syncthreads();
      {
        float gg = ftanh_(gsmem[0][b0][oi] + xv0[0]);
        float ii = fsig (gsmem[1][b0][oi] + xv0[1]);
        float ff = fsig (gsmem[2][b0][oi] + xv0[2]);
        float oo = fsig (gsmem[3][b0][oi] + xv0[3]);
        c0 = ff*c0 + ii*gg;
        const float h0v = oo * ftanh_(c0);
        gg = ftanh_(gsmem[0][b1][oi] + xv1[0]);
        ii = fsig (gsmem[1][b1][oi] + xv1[1]);
        ff = fsig (gsmem[2][b1][oi] + xv1[2]);
        oo = fsig (gsmem[3][b1][oi] + xv1[3]);
        c1 = ff*c1 + ii*gg;
        const float h1v = oo * ftanh_(c1);

        const u16 h0h = f2bf(h0v), h1h = f2bf(h1v);
        const int p0o = __shfl_xor((int)h0h, 1, 64);
        const int p1o = __shfl_xor((int)h1h, 1, 64);
        if ((oi & 1) == 0){
          const uint32_t p0 = (uint32_t)h0h | ((uint32_t)(p0o & 0xffff) << 16);
          const uint32_t p1 = (uint32_t)h1h | ((uint32_t)(p1o & 0xffff) << 16);
          const long d0 = (long)b0*262400 + (long)(t+1)*256 + (og >> 1);
          const long d1 = (long)b1*262400 + (long)(t+1)*256 + (og >> 1);
          __hip_atomic_store(hbuf0 + d0, p0, __ATOMIC_RELAXED, __HIP_MEMORY_SCOPE_AGENT);
          __hip_atomic_store(hbuf0 + d1, p1, __ATOMIC_RELAXED, __HIP_MEMORY_SCOPE_AGENT);
        }
      }
      asm volatile("s_waitcnt vmcnt(0)" ::: "memory");
      __syncthreads();
      if (tid == 0)
        (void)__hip_atomic_fetch_add(cntA + t, 1u, __ATOMIC_RELAXED, __HIP_MEMORY_SCOPE_AGENT);
    }
  } else {
    // ---- layer 1 ----
    bf16x8 wfh[16], wfl[16], wxh[16], wxl[16];
    {
      const long nrow = wid*512 + j*16 + (lane & 15);
      const int kq = (lane >> 4) * 8;
      #pragma unroll
      for (int c = 0; c < 16; ++c){
        wfh[c] = *(const bf16x8*)(Wh1hi + nrow*512 + c*32 + kq);
        wfl[c] = *(const bf16x8*)(Wh1lo + nrow*512 + c*32 + kq);
        wxh[c] = *(const bf16x8*)(Wx1hi + nrow*512 + c*32 + kq);
        wxl[c] = *(const bf16x8*)(Wx1lo + nrow*512 + c*32 + kq);
      }
    }
    float bv[4];
    #pragma unroll
    for (int g = 0; g < 4; ++g) bv[g] = bs1[g*512 + og];

    for (int t = 0; t < TSEQ; ++t){
      if (t > 0){
        if (tid < 64) poll32(cntB + (t-1));
        __syncthreads();
      }
      { // stage h1[t-1] (ring slot (t+3)&3) -> asmem1
        const int tt = ((t+3)&3)*8192;
        u32x4 r0,r1,r2,r3,r4,r5,r6,r7;
        COH_LOAD8(ring+soffR[0]+tt, ring+soffR[1]+tt, ring+soffR[2]+tt, ring+soffR[3]+tt,
                  ring+soffR[4]+tt, ring+soffR[5]+tt, ring+soffR[6]+tt, ring+soffR[7]+tt,
                  r0,r1,r2,r3,r4,r5,r6,r7);
        char* base = &asmem1[(wid*8)*1024 + lane*16];
        *(u32x4*)(base+0*1024)=r0; *(u32x4*)(base+1*1024)=r1;
        *(u32x4*)(base+2*1024)=r2; *(u32x4*)(base+3*1024)=r3;
        *(u32x4*)(base+4*1024)=r4; *(u32x4*)(base+5*1024)=r5;
        *(u32x4*)(base+6*1024)=r6; *(u32x4*)(base+7*1024)=r7;
      }
      if (tid < 64) poll32(cntA + t);
      __syncthreads();                           // asmem1 ready + h0[t] visible
      { // stage h0[t] (slot t+1) -> asmem0
        const int tt = (t+1)*256;
        u32x4 r0,r1,r2,r3,r4,r5,r6,r7;
        COH_LOAD8(hbuf0+soff0[0]+tt, hbuf0+soff0[1]+tt, hbuf0+soff0[2]+tt, hbuf0+soff0[3]+tt,
                  hbuf0+soff0[4]+tt, hbuf0+soff0[5]+tt, hbuf0+soff0[6]+tt, hbuf0+soff0[7]+tt,
                  r0,r1,r2,r3,r4,r5,r6,r7);
        char* base = &asmem0[(wid*8)*1024 + lane*16];
        *(u32x4*)(base+0*1024)=r0; *(u32x4*)(base+1*1024)=r1;
        *(u32x4*)(base+2*1024)=r2; *(u32x4*)(base+3*1024)=r3;
        *(u32x4*)(base+4*1024)=r4; *(u32x4*)(base+5*1024)=r5;
        *(u32x4*)(base+6*1024)=r6; *(u32x4*)(base+7*1024)=r7;
      }
      __syncthreads();

      f32x4 acc0 = {0.f,0.f,0.f,0.f}, acc1 = {0.f,0.f,0.f,0.f};
      #pragma unroll
      for (int c = 0; c < 16; ++c){
        bf16x8 h1a0 = *(const bf16x8*)(&asmem1[((c*2 + 0)*64 + lane)*16]);
        bf16x8 h1a1 = *(const bf16x8*)(&asmem1[((c*2 + 1)*64 + lane)*16]);
        acc0 = __builtin_amdgcn_mfma_f32_16x16x32_bf16(h1a0, wfh[c], acc0, 0,0,0);
        acc1 = __builtin_amdgcn_mfma_f32_16x16x32_bf16(h1a1, wfh[c], acc1, 0,0,0);
        acc0 = __builtin_amdgcn_mfma_f32_16x16x32_bf16(h1a0, wfl[c], acc0, 0,0,0);
        acc1 = __builtin_amdgcn_mfma_f32_16x16x32_bf16(h1a1, wfl[c], acc1, 0,0,0);
        bf16x8 h0a0 = *(const bf16x8*)(&asmem0[((c*2 + 0)*64 + lane)*16]);
        bf16x8 h0a1 = *(const bf16x8*)(&asmem0[((c*2 + 1)*64 + lane)*16]);
        acc0 = __builtin_amdgcn_mfma_f32_16x16x32_bf16(h0a0, wxh[c], acc0, 0,0,0);
        acc1 = __builtin_amdgcn_mfma_f32_16x16x32_bf16(h0a1, wxh[c], acc1, 0,0,0);
        acc0 = __builtin_amdgcn_mfma_f32_16x16x32_bf16(h0a0, wxl[c], acc0, 0,0,0);
        acc1 = __builtin_amdgcn_mfma_f32_16x16x32_bf16(h0a1, wxl[c], acc1, 0,0,0);
      }
      {
        const int bq = (lane >> 4) * 4, ci = lane & 15;
        #pragma unroll
        for (int r = 0; r < 4; ++r){
          gsmem[wid][bq + r][ci]      = acc0[r];
          gsmem[wid][16 + bq + r][ci] = acc1[r];
        }
      }
      __syncthreads();
      {
        float gg = ftanh_(gsmem[0][b0][oi] + bv[0]);
        float ii = fsig (gsmem[1][b0][oi] + bv[1]);
        float ff = fsig (gsmem[2][b0][oi] + bv[2]);
        float oo = fsig (gsmem[3][b0][oi] + bv[3]);
        c0 = ff*c0 + ii*gg;
        const float h0v = oo * ftanh_(c0);
        gg = ftanh_(gsmem[0][b1][oi] + bv[0]);
        ii = fsig (gsmem[1][b1][oi] + bv[1]);
        ff = fsig (gsmem[2][b1][oi] + bv[2]);
        oo = fsig (gsmem[3][b1][oi] + bv[3]);
        c1 = ff*c1 + ii*gg;
        const float h1v = oo * ftanh_(c1);

        if (t == TSEQ-1){
          hfin[b0*512 + og] = h0v;
          hfin[b1*512 + og] = h1v;
        }
        const u16 h0h = f2bf(h0v), h1h = f2bf(h1v);
        const int p0o = __shfl_xor((int)h0h, 1, 64);
        const int p1o = __shfl_xor((int)h1h, 1, 64);
        if ((oi & 1) == 0){
          const uint32_t p0 = (uint32_t)h0h | ((uint32_t)(p0o & 0xffff) << 16);
          const uint32_t p1 = (uint32_t)h1h | ((uint32_t)(p1o & 0xffff) << 16);
          const long d0 = (long)(t&3)*8192 + b0*256 + (og >> 1);
          const long d1 = (long)(t&3)*8192 + b1*256 + (og >> 1);
          __hip_atomic_store(ring + d0, p0, __ATOMIC_RELAXED, __HIP_MEMORY_SCOPE_AGENT);
          __hip_atomic_store(ring + d1, p1, __ATOMIC_RELAXED, __HIP_MEMORY_SCOPE_AGENT);
        }
      }
      asm volatile("s_waitcnt vmcnt(0)" ::: "memory");
      __syncthreads();
      if (tid == 0)
        (void)__hip_atomic_fetch_add(cntB + t, 1u, __ATOMIC_RELAXED, __HIP_MEMORY_SCOPE_AGENT);
    }
  }
}

// ------------------------------------------------------------------- FC out
__global__ void fc_kernel(const float* __restrict__ hfin,
                          const float* __restrict__ fcW, const float* __restrict__ fcb,
                          float* __restrict__ out)
{
  __shared__ float hbufs[512];
  const int b = blockIdx.x, tid = threadIdx.x;
  for (int i = tid; i < 512; i += 256)
    hbufs[i] = hfin[b*512 + i];
  __syncthreads();
  float acc = fcb[tid];
  const float4* w4 = (const float4*)(fcW + tid*512);
  #pragma unroll 8
  for (int k = 0; k < 128; ++k){
    const float4 w = w4[k];
    acc += hbufs[4*k]*w.x + hbufs[4*k+1]*w.y + hbufs[4*k+2]*w.z + hbufs[4*k+3]*w.w;
  }
  out[b*256 + tid] = acc;
}

// ---------------------------------------------------------------- launcher
extern "C" void kernel_launch(void* const* d_in, const int* in_sizes, int n_in,
                              void* d_out, int out_size, void* d_ws, size_t ws_size,
                              hipStream_t stream)
{
  const float* x   = (const float*)d_in[0];
  const float* Wx0 = (const float*)d_in[1];
  const float* bx0 = (const float*)d_in[2];
  const float* Wh0 = (const float*)d_in[3];
  const float* bh0 = (const float*)d_in[4];
  const float* Wx1 = (const float*)d_in[5];
  const float* bx1 = (const float*)d_in[6];
  const float* Wh1 = (const float*)d_in[7];
  const float* bh1 = (const float*)d_in[8];
  const float* fcW = (const float*)d_in[9];
  const float* fcb = (const float*)d_in[10];

  char* ws = (char*)d_ws;
  size_t off = 0;
  auto take = [&](size_t sz){ void* p = ws + off; off += sz; return p; };
  _Float16* xp    = (_Float16*)take((size_t)32768*2048*2);  // 128 MiB (xproj0)
  uint32_t* hbuf0 = (uint32_t*)take((size_t)32*1025*256*4); // layer0 h hist, u32-packed
  u16*   xh      = (u16*)take((size_t)8388608*2);
  u16*   xl      = (u16*)take((size_t)8388608*2);
  u16*   wx0h    = (u16*)take((size_t)524288*2);
  u16*   wx0l    = (u16*)take((size_t)524288*2);
  u16*   wh0h    = (u16*)take((size_t)1048576*2);
  u16*   wh0l    = (u16*)take((size_t)1048576*2);
  u16*   wx1h    = (u16*)take((size_t)1048576*2);
  u16*   wx1l    = (u16*)take((size_t)1048576*2);
  u16*   wh1h    = (u16*)take((size_t)1048576*2);
  u16*   wh1l    = (u16*)take((size_t)1048576*2);
  uint32_t* ring = (uint32_t*)take((size_t)4*32*256*4);     // layer1 h ring
  float* hfin    = (float*)take((size_t)32*512*4);
  float* bs0     = (float*)take(2048*4);
  float* bs1     = (float*)take(2048*4);
  uint32_t* cnts = (uint32_t*)take((size_t)2*1024*4);       // cntA | cntB
  (void)in_sizes; (void)n_in; (void)out_size; (void)ws_size;

  (void)hipMemsetAsync(cnts, 0, (size_t)2*1024*4, stream);

  split_f32<<<4096,256,0,stream>>>(x,   xh,   xl,   8388608);
  split_f32<<<1024,256,0,stream>>>(Wx0, wx0h, wx0l, 524288);
  split_f32<<<2048,256,0,stream>>>(Wh0, wh0h, wh0l, 1048576);
  split_f32<<<2048,256,0,stream>>>(Wx1, wx1h, wx1l, 1048576);
  split_f32<<<2048,256,0,stream>>>(Wh1, wh1h, wh1l, 1048576);
  vec_add<<<8,256,0,stream>>>(bx0, bh0, bs0, 2048);
  vec_add<<<8,256,0,stream>>>(bx1, bh1, bs1, 2048);
  init_state<<<32,256,0,stream>>>(hbuf0, ring);

  dim3 gg(16, 256);
  gemm_split<<<gg,256,0,stream>>>(xh, xl, wx0h, wx0l, bs0, xp, 256);
  lstm_fused<<<64,256,0,stream>>>(xp, wh0h, wh0l, wh1h, wh1l, wx1h, wx1l, bs1,
                                  hbuf0, ring, hfin, cnts, cnts + 1024);
  fc_kernel<<<32,256,0,stream>>>(hfin, fcW, fcb, (float*)d_out);
}

// Round 8
// 5485.558 us; speedup vs baseline: 2.8302x; 1.2574x over previous
//
#include <hip/hip_runtime.h>
#include <hip/hip_bf16.h>
#include <stdint.h>

// 2-layer LSTM, B=32 T=1024 D=256 H=512, fc -> 256.
// R8 = R7 with the 16-operand asm block split into two 8-operand no-wait
// blocks + one drain (fixes gfx950 register-allocation failure at 512thr).
// Fused persistent topology (64 blocks), agent-scope (sc1/MALL) sync via
// __hip_atomic_* builtins; 512-thread blocks so layer-1's 4 weight matrices
// stay register resident; packed per-step counter word -> single-load polls.

typedef __attribute__((ext_vector_type(8))) short bf16x8;
typedef __attribute__((ext_vector_type(4))) float f32x4;
typedef __attribute__((ext_vector_type(4))) unsigned int u32x4;
typedef unsigned short u16;

#define TSEQ 1024

static __device__ __forceinline__ float fsig(float x){ return 1.0f/(1.0f+__expf(-x)); }
static __device__ __forceinline__ float ftanh_(float x){ return 2.0f/(1.0f+__expf(-2.0f*x)) - 1.0f; }
static __device__ __forceinline__ u16 f2bf(float v){
  __hip_bfloat16 b = __float2bfloat16(v);
  return *reinterpret_cast<u16*>(&b);
}
static __device__ __forceinline__ float bf2f(u16 u){
  __hip_bfloat16 b; *reinterpret_cast<u16*>(&b) = u;
  return __bfloat162float(b);
}

// async global->LDS, 16B per lane (GEMM staging)
#define GLD_LDS16(g, l) \
  __builtin_amdgcn_global_load_lds((const __attribute__((address_space(1))) uint32_t*)(g), \
                                   (__attribute__((address_space(3))) uint32_t*)(l), 16, 0, 0)

// 4 pipelined agent-coherent (sc1) 16B loads, NO wait (caller drains)
#define LOAD4_NT(P0,P1,P2,P3, R0,R1,R2,R3)                                     \
  asm volatile(                                                                \
    "global_load_dwordx4 %0, %4, off sc1\n\t"                                  \
    "global_load_dwordx4 %1, %5, off sc1\n\t"                                  \
    "global_load_dwordx4 %2, %6, off sc1\n\t"                                  \
    "global_load_dwordx4 %3, %7, off sc1"                                      \
    : "=&v"(R0),"=&v"(R1),"=&v"(R2),"=&v"(R3)                                  \
    : "v"(P0),"v"(P1),"v"(P2),"v"(P3)                                          \
    : "memory")

#define VM_DRAIN asm volatile("s_waitcnt vmcnt(0)" ::: "memory")

// ---------------------------------------------------------------- utilities
__global__ void split_f32(const float* __restrict__ src, u16* __restrict__ hi,
                          u16* __restrict__ lo, const int n)
{
  for (int i = blockIdx.x*blockDim.x + threadIdx.x; i < n; i += gridDim.x*blockDim.x){
    const float v = src[i];
    const u16 h = f2bf(v);
    hi[i] = h;
    lo[i] = f2bf(v - bf2f(h));
  }
}

__global__ void vec_add(const float* __restrict__ a, const float* __restrict__ b,
                        float* __restrict__ c, const int n)
{
  const int i = blockIdx.x*blockDim.x + threadIdx.x;
  if (i < n) c[i] = a[i] + b[i];
}

// zero h0his slot 0, ring1 slot 3; seed cnt[0].high16 = 32 (B[-1] vacuous)
__global__ void init_state(uint32_t* h0his, uint32_t* ring1, uint32_t* cnt)
{
  const int i = blockIdx.x*256 + threadIdx.x;       // 8192 = 32*256
  h0his[i] = 0;
  ring1[3*8192 + i] = 0;
  if (i == 0) cnt[0] = (32u << 16);
}

// ------------------------------------------------------ split-bf16 MFMA GEMM
// xproj0: C[m][n] = sum_k A[m][k]*W[n][k] + bias[n], M=32768 N=2048 K=256
// 3-term split-bf16: Ah*Wh + Ah*Wl + Al*Wh. Output fp16. (R5-proven, verbatim)
__global__ __launch_bounds__(256, 2) void gemm_split(
    const u16* __restrict__ Ahi, const u16* __restrict__ Alo,
    const u16* __restrict__ Whi, const u16* __restrict__ Wlo,
    const float* __restrict__ bias, _Float16* __restrict__ C,
    const int K)
{
  __shared__ char smem[32768];
  const int tid = threadIdx.x, lane = tid & 63, wid = tid >> 6;
  const int bn = blockIdx.x, bm = blockIdx.y;

  const u16* gptr[8];
  #pragma unroll
  for (int i = 0; i < 8; ++i){
    const int s = i*256 + tid;
    const int mat = s >> 9, tile = (s >> 6) & 7, rr = s & 15, quad = (s >> 4) & 3;
    if (mat == 0 || mat == 3){
      const long row = (long)bm*128 + tile*16 + rr;
      gptr[i] = ((mat == 0) ? Ahi : Alo) + row*(long)K + quad*8;
    } else {
      const long row = (long)bn*128 + tile*16 + rr;
      gptr[i] = ((mat == 1) ? Whi : Wlo) + row*(long)K + quad*8;
    }
  }

  f32x4 acc[4][4];
  #pragma unroll
  for (int a = 0; a < 4; ++a)
    #pragma unroll
    for (int b = 0; b < 4; ++b) acc[a][b] = (f32x4){0.f,0.f,0.f,0.f};

  const int mh = wid & 1, nh = wid >> 1;

  for (int kk = 0; kk < K; kk += 32){
    __syncthreads();
    #pragma unroll
    for (int i = 0; i < 8; ++i)
      GLD_LDS16(gptr[i] + kk, &smem[i*4096 + wid*1024]);
    __syncthreads();
    bf16x8 ah[4], wh_[4], wl_[4], al[4];
    #pragma unroll
    for (int xi = 0; xi < 4; ++xi){
      const int at = mh*4 + xi, wt = nh*4 + xi;
      ah[xi]  = *(const bf16x8*)(&smem[(at*64 + lane)*16]);
      wh_[xi] = *(const bf16x8*)(&smem[8192  + (wt*64 + lane)*16]);
      wl_[xi] = *(const bf16x8*)(&smem[16384 + (wt*64 + lane)*16]);
      al[xi]  = *(const bf16x8*)(&smem[24576 + (at*64 + lane)*16]);
    }
    #pragma unroll
    for (int mi = 0; mi < 4; ++mi)
      #pragma unroll
      for (int ni = 0; ni < 4; ++ni){
        acc[mi][ni] = __builtin_amdgcn_mfma_f32_16x16x32_bf16(ah[mi], wh_[ni], acc[mi][ni], 0,0,0);
        acc[mi][ni] = __builtin_amdgcn_mfma_f32_16x16x32_bf16(ah[mi], wl_[ni], acc[mi][ni], 0,0,0);
        acc[mi][ni] = __builtin_amdgcn_mfma_f32_16x16x32_bf16(al[mi], wh_[ni], acc[mi][ni], 0,0,0);
      }
  }

  const long mbase = (long)bm*128 + mh*64 + (lane >> 4)*4;
  const int  nb    = bn*128 + nh*64 + (lane & 15);
  #pragma unroll
  for (int ni = 0; ni < 4; ++ni){
    const float bv = bias[nb + ni*16];
    #pragma unroll
    for (int mi = 0; mi < 4; ++mi)
      #pragma unroll
      for (int r = 0; r < 4; ++r)
        C[(mbase + mi*16 + r)*2048 + nb + ni*16] = (_Float16)(acc[mi][ni][r] + bv);
  }
}

// -------------------------------------------- fused persistent 2-layer LSTM
// 64 blocks x 512 threads (8 waves). Blocks 0-31: layer 0 (j=blockIdx);
// blocks 32-63: layer 1 (j=blockIdx-32). Wave w: gate g=w>>1, K-half kh=w&1.
// Counters: cnt[t] low16 = #L0 done step t, high16 = #L1 done step t-1.
// h0 full history h0his[t+1][32][256]u32 (slot0 = zeros).
__global__ __launch_bounds__(512, 1) void lstm_fused(
    const _Float16* __restrict__ xp,             // [(b,t)][(g,o)]
    const u16* __restrict__ Wh0hi, const u16* __restrict__ Wh0lo,
    const u16* __restrict__ Wh1hi, const u16* __restrict__ Wh1lo,
    const u16* __restrict__ Wx1hi, const u16* __restrict__ Wx1lo,
    const float* __restrict__ bs1,
    uint32_t* __restrict__ h0his,                // [1025][32][256] u32
    uint32_t* __restrict__ ring1,                // [4][32][256] u32
    float* __restrict__ hfin,                    // [32][512] fp32
    uint32_t* __restrict__ cnt)                  // [1025]
{
  __shared__ char asmem0[32768];                 // 32 rows x 1KB (r = cg*2+mt)
  __shared__ char asmem1[32768];
  __shared__ float gsmem[8][32][16];
  const int tid = threadIdx.x;
  const int lane = tid & 63;
  const int wid = tid >> 6;                      // wave 0..7
  const int g   = wid >> 1;                      // gate (0=G,1=I,2=F,3=O)
  const int kh  = wid & 1;                       // K half
  const int role = blockIdx.x >> 5;
  const int j = blockIdx.x & 31;                 // o-slice

  // staging source offsets (u32 units within a [32][256] slot), rows wid*4+i
  int soff[4];
  #pragma unroll
  for (int i = 0; i < 4; ++i){
    const int r = wid*4 + i, cg = r >> 1, mt = r & 1;
    const int b = mt*16 + (lane & 15);
    const int k = cg*32 + (lane >> 4)*8;
    soff[i] = b*256 + (k >> 1);
  }
  char* const ldst0 = &asmem0[(wid*4)*1024 + lane*16];
  char* const ldst1 = &asmem1[(wid*4)*1024 + lane*16];

  const int b  = tid >> 4, oi = tid & 15;        // per-thread (b, o) cell
  const int og = j*16 + oi;
  float cst = 0.f;

  if (role == 0){
    // ---- layer 0: gates = xp[t] + Wh0 * h0[t-1] ----
    bf16x8 wfh[8], wfl[8];
    {
      const long nrow = g*512 + j*16 + (lane & 15);
      const int kq = (lane >> 4) * 8;
      #pragma unroll
      for (int c = 0; c < 8; ++c){
        const int cg = kh*8 + c;
        wfh[c] = *(const bf16x8*)(Wh0hi + nrow*512 + cg*32 + kq);
        wfl[c] = *(const bf16x8*)(Wh0lo + nrow*512 + cg*32 + kq);
      }
    }
    const long xq = ((long)b << 10)*2048 + j*16 + oi;

    for (int t = 0; t < TSEQ; ++t){
      float xv[4];
      {
        const long base = xq + (long)t*2048;
        #pragma unroll
        for (int gg = 0; gg < 4; ++gg)
          xv[gg] = (float)__builtin_nontemporal_load(xp + base + gg*512);
      }
      if (t > 0){
        if (tid < 64){
          while ((__hip_atomic_load(cnt + (t-1), __ATOMIC_RELAXED,
                                    __HIP_MEMORY_SCOPE_AGENT) & 0xffffu) < 32u){}
        }
        __syncthreads();
      }
      { // stage h0[t-1] (slot t) -> asmem0
        const uint32_t* s = h0his + (long)t*8192;
        u32x4 r0,r1,r2,r3;
        LOAD4_NT(s+soff[0], s+soff[1], s+soff[2], s+soff[3], r0,r1,r2,r3);
        VM_DRAIN;
        *(u32x4*)(ldst0+0*1024)=r0; *(u32x4*)(ldst0+1*1024)=r1;
        *(u32x4*)(ldst0+2*1024)=r2; *(u32x4*)(ldst0+3*1024)=r3;
      }
      __syncthreads();

      f32x4 acc0 = {0.f,0.f,0.f,0.f}, acc1 = {0.f,0.f,0.f,0.f};
      #pragma unroll
      for (int c = 0; c < 8; ++c){
        const int cg = kh*8 + c;
        bf16x8 a0 = *(const bf16x8*)(&asmem0[((cg*2 + 0)*64 + lane)*16]);
        bf16x8 a1 = *(const bf16x8*)(&asmem0[((cg*2 + 1)*64 + lane)*16]);
        acc0 = __builtin_amdgcn_mfma_f32_16x16x32_bf16(a0, wfh[c], acc0, 0,0,0);
        acc1 = __builtin_amdgcn_mfma_f32_16x16x32_bf16(a1, wfh[c], acc1, 0,0,0);
        acc0 = __builtin_amdgcn_mfma_f32_16x16x32_bf16(a0, wfl[c], acc0, 0,0,0);
        acc1 = __builtin_amdgcn_mfma_f32_16x16x32_bf16(a1, wfl[c], acc1, 0,0,0);
      }
      {
        const int bq = (lane >> 4) * 4, ci = lane & 15;
        #pragma unroll
        for (int r = 0; r < 4; ++r){
          gsmem[wid][bq + r][ci]      = acc0[r];
          gsmem[wid][16 + bq + r][ci] = acc1[r];
        }
      }
      __syncthreads();
      {
        const float gv = ftanh_(gsmem[0][b][oi] + gsmem[1][b][oi] + xv[0]);
        const float iv = fsig (gsmem[2][b][oi] + gsmem[3][b][oi] + xv[1]);
        const float fv = fsig (gsmem[4][b][oi] + gsmem[5][b][oi] + xv[2]);
        const float ov = fsig (gsmem[6][b][oi] + gsmem[7][b][oi] + xv[3]);
        cst = fv*cst + iv*gv;
        const float hv = ov * ftanh_(cst);
        const u16 hh = f2bf(hv);
        const int po = __shfl_xor((int)hh, 1, 64);
        if ((oi & 1) == 0){
          const uint32_t p = (uint32_t)hh | ((uint32_t)(po & 0xffff) << 16);
          __hip_atomic_store(h0his + (long)(t+1)*8192 + b*256 + (og >> 1), p,
                             __ATOMIC_RELAXED, __HIP_MEMORY_SCOPE_AGENT);
        }
      }
      VM_DRAIN;
      __syncthreads();
      if (tid == 0)
        (void)__hip_atomic_fetch_add(cnt + t, 1u, __ATOMIC_RELAXED,
                                     __HIP_MEMORY_SCOPE_AGENT);
    }
  } else {
    // ---- layer 1: gates = bs1 + Wx1*h0[t] + Wh1*h1[t-1] ----
    bf16x8 wfh[8], wfl[8], wxh[8], wxl[8];
    {
      const long nrow = g*512 + j*16 + (lane & 15);
      const int kq = (lane >> 4) * 8;
      #pragma unroll
      for (int c = 0; c < 8; ++c){
        const int cg = kh*8 + c;
        wfh[c] = *(const bf16x8*)(Wh1hi + nrow*512 + cg*32 + kq);
        wfl[c] = *(const bf16x8*)(Wh1lo + nrow*512 + cg*32 + kq);
        wxh[c] = *(const bf16x8*)(Wx1hi + nrow*512 + cg*32 + kq);
        wxl[c] = *(const bf16x8*)(Wx1lo + nrow*512 + cg*32 + kq);
      }
    }
    float bv[4];
    #pragma unroll
    for (int gg = 0; gg < 4; ++gg) bv[gg] = bs1[gg*512 + og];

    for (int t = 0; t < TSEQ; ++t){
      if (tid < 64){
        // one word: low16 = A[t] (h0[t] ready), high16 = B[t-1] (ring free)
        for (;;){
          const uint32_t v = __hip_atomic_load(cnt + t, __ATOMIC_RELAXED,
                                               __HIP_MEMORY_SCOPE_AGENT);
          if ((v & 0xffffu) >= 32u && (v >> 16) >= 32u) break;
        }
      }
      __syncthreads();
      { // h0[t] (slot t+1) -> asmem0 ; h1[t-1] (ring slot (t+3)&3) -> asmem1
        const uint32_t* s0 = h0his + (long)(t+1)*8192;
        const uint32_t* s1 = ring1 + ((t+3)&3)*8192;
        u32x4 r0,r1,r2,r3,q0,q1,q2,q3;
        LOAD4_NT(s0+soff[0], s0+soff[1], s0+soff[2], s0+soff[3], r0,r1,r2,r3);
        LOAD4_NT(s1+soff[0], s1+soff[1], s1+soff[2], s1+soff[3], q0,q1,q2,q3);
        VM_DRAIN;
        *(u32x4*)(ldst0+0*1024)=r0; *(u32x4*)(ldst0+1*1024)=r1;
        *(u32x4*)(ldst0+2*1024)=r2; *(u32x4*)(ldst0+3*1024)=r3;
        *(u32x4*)(ldst1+0*1024)=q0; *(u32x4*)(ldst1+1*1024)=q1;
        *(u32x4*)(ldst1+2*1024)=q2; *(u32x4*)(ldst1+3*1024)=q3;
      }
      __syncthreads();

      f32x4 acc0 = {0.f,0.f,0.f,0.f}, acc1 = {0.f,0.f,0.f,0.f};
      #pragma unroll
      for (int c = 0; c < 8; ++c){
        const int cg = kh*8 + c;
        bf16x8 h1a0 = *(const bf16x8*)(&asmem1[((cg*2 + 0)*64 + lane)*16]);
        bf16x8 h1a1 = *(const bf16x8*)(&asmem1[((cg*2 + 1)*64 + lane)*16]);
        acc0 = __builtin_amdgcn_mfma_f32_16x16x32_bf16(h1a0, wfh[c], acc0, 0,0,0);
        acc1 = __builtin_amdgcn_mfma_f32_16x16x32_bf16(h1a1, wfh[c], acc1, 0,0,0);
        acc0 = __builtin_amdgcn_mfma_f32_16x16x32_bf16(h1a0, wfl[c], acc0, 0,0,0);
        acc1 = __builtin_amdgcn_mfma_f32_16x16x32_bf16(h1a1, wfl[c], acc1, 0,0,0);
        bf16x8 h0a0 = *(const bf16x8*)(&asmem0[((cg*2 + 0)*64 + lane)*16]);
        bf16x8 h0a1 = *(const bf16x8*)(&asmem0[((cg*2 + 1)*64 + lane)*16]);
        acc0 = __builtin_amdgcn_mfma_f32_16x16x32_bf16(h0a0, wxh[c], acc0, 0,0,0);
        acc1 = __builtin_amdgcn_mfma_f32_16x16x32_bf16(h0a1, wxh[c], acc1, 0,0,0);
        acc0 = __builtin_amdgcn_mfma_f32_16x16x32_bf16(h0a0, wxl[c], acc0, 0,0,0);
        acc1 = __builtin_amdgcn_mfma_f32_16x16x32_bf16(h0a1, wxl[c], acc1, 0,0,0);
      }
      {
        const int bq = (lane >> 4) * 4, ci = lane & 15;
        #pragma unroll
        for (int r = 0; r < 4; ++r){
          gsmem[wid][bq + r][ci]      = acc0[r];
          gsmem[wid][16 + bq + r][ci] = acc1[r];
        }
      }
      __syncthreads();
      {
        const float gv = ftanh_(gsmem[0][b][oi] + gsmem[1][b][oi] + bv[0]);
        const float iv = fsig (gsmem[2][b][oi] + gsmem[3][b][oi] + bv[1]);
        const float fv = fsig (gsmem[4][b][oi] + gsmem[5][b][oi] + bv[2]);
        const float ov = fsig (gsmem[6][b][oi] + gsmem[7][b][oi] + bv[3]);
        cst = fv*cst + iv*gv;
        const float hv = ov * ftanh_(cst);
        if (t == TSEQ-1) hfin[b*512 + og] = hv;
        const u16 hh = f2bf(hv);
        const int po = __shfl_xor((int)hh, 1, 64);
        if ((oi & 1) == 0){
          const uint32_t p = (uint32_t)hh | ((uint32_t)(po & 0xffff) << 16);
          __hip_atomic_store(ring1 + (t&3)*8192 + b*256 + (og >> 1), p,
                             __ATOMIC_RELAXED, __HIP_MEMORY_SCOPE_AGENT);
        }
      }
      VM_DRAIN;
      __syncthreads();
      if (tid == 0)
        (void)__hip_atomic_fetch_add(cnt + (t+1), 1u << 16, __ATOMIC_RELAXED,
                                     __HIP_MEMORY_SCOPE_AGENT);
    }
  }
}

// ------------------------------------------------------------------- FC out
__global__ void fc_kernel(const float* __restrict__ hfin,
                          const float* __restrict__ fcW, const float* __restrict__ fcb,
                          float* __restrict__ out)
{
  __shared__ float hbufs[512];
  const int b = blockIdx.x, tid = threadIdx.x;
  for (int i = tid; i < 512; i += 256)
    hbufs[i] = hfin[b*512 + i];
  __syncthreads();
  float acc = fcb[tid];
  const float4* w4 = (const float4*)(fcW + tid*512);
  #pragma unroll 8
  for (int k = 0; k < 128; ++k){
    const float4 w = w4[k];
    acc += hbufs[4*k]*w.x + hbufs[4*k+1]*w.y + hbufs[4*k+2]*w.z + hbufs[4*k+3]*w.w;
  }
  out[b*256 + tid] = acc;
}

// ---------------------------------------------------------------- launcher
extern "C" void kernel_launch(void* const* d_in, const int* in_sizes, int n_in,
                              void* d_out, int out_size, void* d_ws, size_t ws_size,
                              hipStream_t stream)
{
  const float* x   = (const float*)d_in[0];
  const float* Wx0 = (const float*)d_in[1];
  const float* bx0 = (const float*)d_in[2];
  const float* Wh0 = (const float*)d_in[3];
  const float* bh0 = (const float*)d_in[4];
  const float* Wx1 = (const float*)d_in[5];
  const float* bx1 = (const float*)d_in[6];
  const float* Wh1 = (const float*)d_in[7];
  const float* bh1 = (const float*)d_in[8];
  const float* fcW = (const float*)d_in[9];
  const float* fcb = (const float*)d_in[10];

  char* ws = (char*)d_ws;
  size_t off = 0;
  auto take = [&](size_t sz){ void* p = ws + off; off += sz; return p; };
  _Float16* xp    = (_Float16*)take((size_t)32768*2048*2);   // 128 MiB
  uint32_t* h0his = (uint32_t*)take((size_t)1025*8192*4);    // 33.6 MB h0 history
  u16*   xh      = (u16*)take((size_t)8388608*2);
  u16*   xl      = (u16*)take((size_t)8388608*2);
  u16*   wx0h    = (u16*)take((size_t)524288*2);
  u16*   wx0l    = (u16*)take((size_t)524288*2);
  u16*   wh0h    = (u16*)take((size_t)1048576*2);
  u16*   wh0l    = (u16*)take((size_t)1048576*2);
  u16*   wx1h    = (u16*)take((size_t)1048576*2);
  u16*   wx1l    = (u16*)take((size_t)1048576*2);
  u16*   wh1h    = (u16*)take((size_t)1048576*2);
  u16*   wh1l    = (u16*)take((size_t)1048576*2);
  uint32_t* ring1 = (uint32_t*)take((size_t)4*8192*4);       // 128 KB h1 ring
  float* hfin    = (float*)take((size_t)32*512*4);
  float* bs0     = (float*)take(2048*4);
  float* bs1     = (float*)take(2048*4);
  uint32_t* cnt  = (uint32_t*)take((size_t)1056*4);
  (void)in_sizes; (void)n_in; (void)out_size; (void)ws_size;

  (void)hipMemsetAsync(cnt, 0, (size_t)1056*4, stream);

  split_f32<<<4096,256,0,stream>>>(x,   xh,   xl,   8388608);
  split_f32<<<1024,256,0,stream>>>(Wx0, wx0h, wx0l, 524288);
  split_f32<<<2048,256,0,stream>>>(Wh0, wh0h, wh0l, 1048576);
  split_f32<<<2048,256,0,stream>>>(Wx1, wx1h, wx1l, 1048576);
  split_f32<<<2048,256,0,stream>>>(Wh1, wh1h, wh1l, 1048576);
  vec_add<<<8,256,0,stream>>>(bx0, bh0, bs0, 2048);
  vec_add<<<8,256,0,stream>>>(bx1, bh1, bs1, 2048);
  init_state<<<32,256,0,stream>>>(h0his, ring1, cnt);

  dim3 gg(16, 256);
  gemm_split<<<gg,256,0,stream>>>(xh, xl, wx0h, wx0l, bs0, xp, 256);
  lstm_fused<<<64,512,0,stream>>>(xp, wh0h, wh0l, wh1h, wh1l, wx1h, wx1l, bs1,
                                  h0his, ring1, hfin, cnt);
  fc_kernel<<<32,256,0,stream>>>(hfin, fcW, fcb, (float*)d_out);
}